// Round 1
// baseline (680.800 us; speedup 1.0000x reference)
//
#include <hip/hip_runtime.h>
#include <hip/hip_bf16.h>

typedef __attribute__((ext_vector_type(8))) short short8;
typedef __attribute__((ext_vector_type(4))) float float4v;

#define BM 128
#define BK 32
#define LDSK 40   // padded bf16 row length: 80 B row stride = 20 banks -> 2-way (free)

struct alignas(8) BF4 { unsigned short x, y, z, w; };
struct alignas(16) I4 { int x, y, z, w; };

__device__ __forceinline__ unsigned short f2bf(float f) {
    union { float f; unsigned u; } v; v.f = f;
    unsigned u = v.u + (0x7FFFu + ((v.u >> 16) & 1u));   // round-to-nearest-even
    return (unsigned short)(u >> 16);
}

// Stage a 128x32 fp32 tile (row stride ld) into bf16 LDS [128][LDSK].
__device__ __forceinline__ void stage_f32_tile(const float* __restrict__ src, long ld,
                                               unsigned short* lds, int t) {
    const int rr  = t >> 3;          // 0..31
    const int col = (t & 7) << 2;    // 0..28 step 4
    #pragma unroll
    for (int r = 0; r < 4; ++r) {
        const int row = rr + r * 32;
        const float4 v = *(const float4*)(src + (long)row * ld + col);
        BF4 o; o.x = f2bf(v.x); o.y = f2bf(v.y); o.z = f2bf(v.z); o.w = f2bf(v.w);
        *(BF4*)(lds + row * LDSK + col) = o;
    }
}

__device__ __forceinline__ int find_expert(const int* __restrict__ bspe, int row0) {
    int e = 0, off = 0;
    #pragma unroll
    for (int i = 0; i < 8; ++i) {
        int s = bspe[i];
        if (row0 < off + s) { e = i; break; }
        off += s;
    }
    return e;
}

// Kernel 1: per expert, h = silu(x@Wu^T) * (x@Wg^T), h stored bf16 in ws.
// Block computes a 128-row x 64-hcol tile of h (i.e., 128x128 virtual C with
// 64 up cols + 64 gate cols). grid = (H/64=16, M/128=128).
__global__ __launch_bounds__(256) void moe_up_gate(
    const float* __restrict__ x, const float* __restrict__ wug,
    const int* __restrict__ bspe, unsigned short* __restrict__ hws) {
    __shared__ alignas(16) unsigned short As[BM * LDSK];
    __shared__ alignas(16) unsigned short Bs[BM * LDSK];

    const int t = threadIdx.x;
    const int lane = t & 63;
    const int w = t >> 6;
    const int wr = w >> 1, wc = w & 1;
    const int bm = blockIdx.y;
    const int h0 = blockIdx.x * 64;
    const int row0 = bm * BM;

    const int e = find_expert(bspe, row0);

    const float* abase = x + (long)row0 * 2048;
    const float* bup = wug + ((long)e * 2048 + h0) * 2048;           // up rows
    const float* bgt = wug + ((long)e * 2048 + 1024 + h0) * 2048;    // gate rows

    float4v acc[4][4];
    #pragma unroll
    for (int m = 0; m < 4; ++m)
        #pragma unroll
        for (int n = 0; n < 4; ++n)
            acc[m][n] = (float4v){0.f, 0.f, 0.f, 0.f};

    const int k8 = (lane >> 4) << 3;           // 0,8,16,24
    const int am = wr * 64 + (lane & 15);      // A row in tile (+m*16)
    const int l15 = lane & 15;

    for (int k0 = 0; k0 < 2048; k0 += BK) {
        __syncthreads();
        stage_f32_tile(abase + k0, 2048, As, t);
        {   // B tile: rows 0..63 = up, rows 64..127 = gate
            const int rr  = t >> 3;
            const int col = (t & 7) << 2;
            #pragma unroll
            for (int r = 0; r < 4; ++r) {
                const int row = rr + r * 32;
                const float* p = (row < 64 ? bup + (long)row * 2048
                                           : bgt + (long)(row - 64) * 2048) + k0 + col;
                const float4 v = *(const float4*)p;
                BF4 o; o.x = f2bf(v.x); o.y = f2bf(v.y); o.z = f2bf(v.z); o.w = f2bf(v.w);
                *(BF4*)(Bs + row * LDSK + col) = o;
            }
        }
        __syncthreads();

        short8 a[4], b[4];
        #pragma unroll
        for (int m = 0; m < 4; ++m)
            a[m] = *(const short8*)(As + (am + m * 16) * LDSK + k8);
        #pragma unroll
        for (int n = 0; n < 4; ++n) {
            // n-tiles 0,1: up rows wc*32+n*16 ; n-tiles 2,3: gate rows 64+wc*32+(n-2)*16
            const int rb = (n < 2) ? (wc * 32 + n * 16) : (64 + wc * 32 + (n - 2) * 16);
            b[n] = *(const short8*)(Bs + (rb + l15) * LDSK + k8);
        }
        #pragma unroll
        for (int m = 0; m < 4; ++m)
            #pragma unroll
            for (int n = 0; n < 4; ++n)
                acc[m][n] = __builtin_amdgcn_mfma_f32_16x16x32_bf16(a[m], b[n], acc[m][n], 0, 0, 0);
    }

    // Epilogue: h = silu(up) * gate. acc[m][n] (up) pairs with acc[m][n+2] (gate), same lane.
    const int rbase = row0 + wr * 64 + (lane >> 4) * 4;
    const int cbase = h0 + wc * 32 + l15;
    #pragma unroll
    for (int m = 0; m < 4; ++m)
        #pragma unroll
        for (int n = 0; n < 2; ++n)
            #pragma unroll
            for (int q = 0; q < 4; ++q) {
                const float u = acc[m][n][q];
                const float g = acc[m][n + 2][q];
                const float s = u / (1.f + __expf(-u));
                const int row = rbase + m * 16 + q;
                const int col = cbase + n * 16;
                hws[(long)row * 1024 + col] = f2bf(s * g);
            }
}

// Kernel 2: out = h @ Wd_e^T. A = bf16 h in ws (ld=1024), B = w_down fp32
// (ld=8192, expert col offset e*1024). grid = (D/128=16, M/128=128).
__global__ __launch_bounds__(256) void moe_down(
    const unsigned short* __restrict__ hws, const float* __restrict__ wd,
    const int* __restrict__ bspe, float* __restrict__ out) {
    __shared__ alignas(16) unsigned short As[BM * LDSK];
    __shared__ alignas(16) unsigned short Bs[BM * LDSK];

    const int t = threadIdx.x;
    const int lane = t & 63;
    const int w = t >> 6;
    const int wr = w >> 1, wc = w & 1;
    const int bm = blockIdx.y;
    const int n0 = blockIdx.x * BM;
    const int row0 = bm * BM;

    const int e = find_expert(bspe, row0);

    const unsigned short* abase = hws + (long)row0 * 1024;
    const float* bbase = wd + (long)n0 * 8192 + e * 1024;

    float4v acc[4][4];
    #pragma unroll
    for (int m = 0; m < 4; ++m)
        #pragma unroll
        for (int n = 0; n < 4; ++n)
            acc[m][n] = (float4v){0.f, 0.f, 0.f, 0.f};

    const int k8 = (lane >> 4) << 3;
    const int am = wr * 64 + (lane & 15);
    const int l15 = lane & 15;

    for (int k0 = 0; k0 < 1024; k0 += BK) {
        __syncthreads();
        {   // A: 128x32 bf16 copy, 16B vector moves
            const int row = t >> 2;            // 0..63
            const int col = (t & 3) << 3;      // 0,8,16,24
            #pragma unroll
            for (int r = 0; r < 2; ++r) {
                const I4 v = *(const I4*)(abase + (long)(row + r * 64) * 1024 + k0 + col);
                *(I4*)(As + (row + r * 64) * LDSK + col) = v;
            }
        }
        stage_f32_tile(bbase + k0, 8192, Bs, t);
        __syncthreads();

        short8 a[4], b[4];
        #pragma unroll
        for (int m = 0; m < 4; ++m)
            a[m] = *(const short8*)(As + (am + m * 16) * LDSK + k8);
        #pragma unroll
        for (int n = 0; n < 4; ++n)
            b[n] = *(const short8*)(Bs + (wc * 64 + n * 16 + l15) * LDSK + k8);
        #pragma unroll
        for (int m = 0; m < 4; ++m)
            #pragma unroll
            for (int n = 0; n < 4; ++n)
                acc[m][n] = __builtin_amdgcn_mfma_f32_16x16x32_bf16(a[m], b[n], acc[m][n], 0, 0, 0);
    }

    const int rbase = row0 + wr * 64 + (lane >> 4) * 4;
    const int cbase = n0 + wc * 64 + l15;
    #pragma unroll
    for (int m = 0; m < 4; ++m)
        #pragma unroll
        for (int n = 0; n < 4; ++n)
            #pragma unroll
            for (int q = 0; q < 4; ++q)
                out[(long)(rbase + m * 16 + q) * 2048 + cbase + n * 16] = acc[m][n][q];
}

extern "C" void kernel_launch(void* const* d_in, const int* in_sizes, int n_in,
                              void* d_out, int out_size, void* d_ws, size_t ws_size,
                              hipStream_t stream) {
    const float* x   = (const float*)d_in[0];
    const float* wug = (const float*)d_in[1];
    const float* wd  = (const float*)d_in[2];
    const int*  bspe = (const int*)d_in[3];
    float* out = (float*)d_out;
    unsigned short* hws = (unsigned short*)d_ws;   // 16384 x 1024 bf16 = 33.5 MB

    moe_up_gate<<<dim3(16, 128), dim3(256), 0, stream>>>(x, wug, bspe, hws);
    moe_down  <<<dim3(16, 128), dim3(256), 0, stream>>>(hws, wd, bspe, out);
}